// Round 4
// baseline (32313.467 us; speedup 1.0000x reference)
//
#include <hip/hip_runtime.h>
#include <stdint.h>
#include <math.h>

#define BATCH 32768
#define LDIM 128
#define HID 20
#define NG 80                       // 4*HID

// =====================================================================
// eps: jax.random.normal(key(42), (128,32768), f32) with the MODERN
// (jax_threefry_partitionable=True, default since ~0.4.36) counter
// scheme: for flat index n, counters = (hi32(n), lo32(n)) = (0, n),
// 32-bit output = o0 ^ o1. Threefry core verified against Random123
// KAT (key 0,0 ctr 0,0 -> 0x6b200159, 0x99ba4efe) by hand trace.
// Uniform map + Giles erfinv follow XLA f32 ops, separately rounded.
// =====================================================================

__device__ __forceinline__ void threefry2x32(uint32_t x0, uint32_t x1,
                                             uint32_t& o0, uint32_t& o1) {
  const uint32_t k0 = 0u, k1 = 42u;
  const uint32_t k2 = k0 ^ k1 ^ 0x1BD11BDAu;
  uint32_t v0 = x0 + k0, v1 = x1 + k1;
#define TF_R(r) { v0 += v1; v1 = (v1 << (r)) | (v1 >> (32 - (r))); v1 ^= v0; }
  TF_R(13) TF_R(15) TF_R(26) TF_R(6)
  v0 += k1; v1 += k2 + 1u;
  TF_R(17) TF_R(29) TF_R(16) TF_R(24)
  v0 += k2; v1 += k0 + 2u;
  TF_R(13) TF_R(15) TF_R(26) TF_R(6)
  v0 += k0; v1 += k1 + 3u;
  TF_R(17) TF_R(29) TF_R(16) TF_R(24)
  v0 += k1; v1 += k2 + 4u;
  TF_R(13) TF_R(15) TF_R(26) TF_R(6)
  v0 += k2; v1 += k0 + 5u;
#undef TF_R
  o0 = v0; o1 = v1;
}

// XLA ErfInv32: w = -log1p(-x*x); Giles polynomial, separately-rounded f32.
__device__ __forceinline__ float erfinv_xla_f32(float x) {
  float t = __fmul_rn(x, x);
  float w = -(float)log1p(-(double)t);   // correctly-rounded f32 log1p
  float p;
  if (w < 5.0f) {
    w = __fadd_rn(w, -2.5f);
    p = 2.81022636e-08f;
    p = __fadd_rn(__fmul_rn(p, w), 3.43273939e-07f);
    p = __fadd_rn(__fmul_rn(p, w), -3.5233877e-06f);
    p = __fadd_rn(__fmul_rn(p, w), -4.39150654e-06f);
    p = __fadd_rn(__fmul_rn(p, w), 0.00021858087f);
    p = __fadd_rn(__fmul_rn(p, w), -0.00125372503f);
    p = __fadd_rn(__fmul_rn(p, w), -0.00417768164f);
    p = __fadd_rn(__fmul_rn(p, w), 0.246640727f);
    p = __fadd_rn(__fmul_rn(p, w), 1.50140941f);
  } else {
    w = __fadd_rn(__fsqrt_rn(w), -3.0f);
    p = -0.000200214257f;
    p = __fadd_rn(__fmul_rn(p, w), 0.000100950558f);
    p = __fadd_rn(__fmul_rn(p, w), 0.00134934322f);
    p = __fadd_rn(__fmul_rn(p, w), -0.00367342844f);
    p = __fadd_rn(__fmul_rn(p, w), 0.00573950773f);
    p = __fadd_rn(__fmul_rn(p, w), -0.0076224613f);
    p = __fadd_rn(__fmul_rn(p, w), 0.00943887047f);
    p = __fadd_rn(__fmul_rn(p, w), 1.00167406f);
    p = __fadd_rn(__fmul_rn(p, w), 2.83297682f);
  }
  return __fmul_rn(p, x);
}

// eps[t][b] — partitionable counter scheme
__device__ __forceinline__ float eps_val(int t, int b) {
  uint32_t n = (uint32_t)t * 32768u + (uint32_t)b;   // flat index < 2^32 -> hi = 0
  uint32_t o0, o1;
  threefry2x32(0u, n, o0, o1);
  uint32_t bits = o0 ^ o1;
  const float lo    = __uint_as_float(0xBF7FFFFFu);   // nextafter(-1,0) f32
  const float sqrt2 = __uint_as_float(0x3FB504F3u);   // float32(sqrt(2))
  float f = __fadd_rn(__uint_as_float((bits >> 9) | 0x3F800000u), -1.0f); // [0,1)
  float u = __fadd_rn(__fmul_rn(f, 2.0f), lo);        // (maxval-minval) == 2.0f
  u = fmaxf(u, lo);
  return __fmul_rn(sqrt2, erfinv_xla_f32(u));
}

// ---------- fp64 activation helpers (tracks np fp64 ref) ----------
__device__ __forceinline__ double sigm_d(double x) {
  if (x >= 0.0) { return 1.0 / (1.0 + exp(-x)); }
  double e = exp(x); return e / (1.0 + e);
}
__device__ __forceinline__ double leaky_d(double x) {
  return (x >= 0.0) ? x : 0.01 * x;
}

__global__ __launch_bounds__(64, 1) void sampler_kernel(
    const float* __restrict__ mu, const float* __restrict__ log_var,
    const float* __restrict__ W_ih1, const float* __restrict__ W_hh1,
    const float* __restrict__ b_ih1, const float* __restrict__ b_hh1,
    const float* __restrict__ W_ih2, const float* __restrict__ W_hh2,
    const float* __restrict__ b_ih2, const float* __restrict__ b_hh2,
    float* __restrict__ out) {
  __shared__ float  sWihT[127 * NG];    // fp32: [col j][gate g]  (transposed W_ih1)
  __shared__ double sWhh1[NG * HID];    // fp64: [gate g][k]
  __shared__ double sWih2T[40 * 8];     // fp64: [k][j]           (transposed W_ih2)
  __shared__ double sWhh2[16];          // fp64: [j][0..1]
  __shared__ double sB1[NG];            // fp64: b_ih1 + b_hh1
  __shared__ double sB2[8];             // fp64: b_ih2 + b_hh2

  const int tid = threadIdx.x;
  for (int i = tid; i < 127 * NG; i += 64) {
    int g = i / 127, j = i - g * 127;
    sWihT[j * NG + g] = W_ih1[i];
  }
  for (int i = tid; i < NG * HID; i += 64) sWhh1[i] = (double)W_hh1[i];
  for (int i = tid; i < 320; i += 64) {
    int j = i / 40, k = i - j * 40;
    sWih2T[k * 8 + j] = (double)W_ih2[i];
  }
  if (tid < 16) sWhh2[tid] = (double)W_hh2[tid];
  if (tid < 8)  sB2[tid] = (double)b_ih2[tid] + (double)b_hh2[tid];
  for (int i = tid; i < NG; i += 64) sB1[i] = (double)b_ih1[i] + (double)b_hh1[i];
  __syncthreads();

  const int b = blockIdx.x * 64 + tid;
  const float* mrow = mu + (size_t)b * LDIM;

  // first_input = eps[0]*exp(0.5*log_var[:,0]) + mu[:,0]
  double eps0 = (double)eps_val(0, b);
  double m0 = (double)mrow[0];
  double fi = eps0 * exp(0.5 * (double)log_var[(size_t)b * LDIM]) + m0;

  // prefix accumulator of x @ W_ih1^T; step-1 input = first_input in col 0
  double acc[NG];
#pragma unroll
  for (int g = 0; g < NG; ++g) acc[g] = fi * (double)sWihT[g];

  double h[HID], c[HID];
#pragma unroll
  for (int k = 0; k < HID; ++k) { h[k] = 0.0; c[k] = 0.0; }
  double h2a = 0.0, h2b = 0.0, c2a = 0.0, c2b = 0.0;

  float* out_mu = out;
  float* out_lv = out + (size_t)BATCH * LDIM;
  float* out_sp = out + 2 * (size_t)BATCH * LDIM;
  const size_t rowoff = (size_t)b * LDIM;
  out_mu[rowoff] = 0.0f;
  out_lv[rowoff] = 1.0f;
  out_sp[rowoff] = (float)fi;

  for (int t = 1; t < LDIM; ++t) {
    // ---- maintain acc = (mu cols 0..t-1) @ W_ih1^T ----
    if (t >= 2) {
      if (t == 2) {
        double d0 = m0 - fi;   // col 0 switches first_input -> mu[:,0]
#pragma unroll
        for (int g = 0; g < NG; ++g) acc[g] = fma(d0, (double)sWihT[g], acc[g]);
      }
      double xm = (double)mrow[t - 1];
      const float* col = &sWihT[(t - 1) * NG];
#pragma unroll
      for (int g = 0; g < NG; ++g) acc[g] = fma(xm, (double)col[g], acc[g]);
    }

    // ---- LSTM2 gate init: biases + h2 @ W_hh2^T ----
    double g2[8];
#pragma unroll
    for (int j = 0; j < 8; ++j)
      g2[j] = sB2[j] + h2a * sWhh2[2 * j] + h2b * sWhh2[2 * j + 1];

    // ---- LSTM1 gates + cell, fused LSTM2 gate accumulation ----
    double hn[HID];
#pragma unroll
    for (int k = 0; k < HID; ++k) {
      double si = acc[k]      + sB1[k];
      double sf = acc[20 + k] + sB1[20 + k];
      double sg = acc[40 + k] + sB1[40 + k];
      double so = acc[60 + k] + sB1[60 + k];
      const double* wi = &sWhh1[(k)      * HID];
      const double* wf = &sWhh1[(20 + k) * HID];
      const double* wg = &sWhh1[(40 + k) * HID];
      const double* wo = &sWhh1[(60 + k) * HID];
#pragma unroll
      for (int j = 0; j < HID; ++j) {
        double hj = h[j];
        si = fma(hj, wi[j], si);
        sf = fma(hj, wf[j], sf);
        sg = fma(hj, wg[j], sg);
        so = fma(hj, wo[j], so);
      }
      double ik = sigm_d(si), fk = sigm_d(sf), gk = tanh(sg), ok = sigm_d(so);
      double cn = fma(fk, c[k], ik * gk);
      c[k] = cn;
      double hk = ok * tanh(cn);
      hn[k] = hk;
      double lh = leaky_d(hk);   // leaky_relu(h1)
      double lc = leaky_d(cn);   // leaky_relu(c1)
      const double* uu = &sWih2T[k * 8];
      const double* vv = &sWih2T[(20 + k) * 8];
#pragma unroll
      for (int j = 0; j < 8; ++j) {
        g2[j] = fma(lh, uu[j], g2[j]);
        g2[j] = fma(lc, vv[j], g2[j]);
      }
    }
#pragma unroll
    for (int k = 0; k < HID; ++k) h[k] = hn[k];

    // ---- LSTM2 cell (H2 = 2): i=g2[0:2], f=g2[2:4], g=g2[4:6], o=g2[6:8] ----
    double i20 = sigm_d(g2[0]), i21 = sigm_d(g2[1]);
    double f20 = sigm_d(g2[2]), f21 = sigm_d(g2[3]);
    double t20 = tanh(g2[4]),   t21 = tanh(g2[5]);
    double o20 = sigm_d(g2[6]), o21 = sigm_d(g2[7]);
    c2a = fma(f20, c2a, i20 * t20);
    c2b = fma(f21, c2b, i21 * t21);
    h2a = o20 * tanh(c2a);
    h2b = o21 * tanh(c2b);

    // ---- sample + store ----
    double eps_t = (double)eps_val(t, b);
    double sp = fma(eps_t, exp(0.5 * h2b), h2a);
    out_mu[rowoff + t] = (float)h2a;
    out_lv[rowoff + t] = (float)h2b;
    out_sp[rowoff + t] = (float)sp;
  }
}

extern "C" void kernel_launch(void* const* d_in, const int* in_sizes, int n_in,
                              void* d_out, int out_size, void* d_ws, size_t ws_size,
                              hipStream_t stream) {
  (void)in_sizes; (void)n_in; (void)d_ws; (void)ws_size; (void)out_size;
  const float* mu      = (const float*)d_in[0];
  const float* log_var = (const float*)d_in[1];
  const float* W_ih1   = (const float*)d_in[2];
  const float* W_hh1   = (const float*)d_in[3];
  const float* b_ih1   = (const float*)d_in[4];
  const float* b_hh1   = (const float*)d_in[5];
  const float* W_ih2   = (const float*)d_in[6];
  const float* W_hh2   = (const float*)d_in[7];
  const float* b_ih2   = (const float*)d_in[8];
  const float* b_hh2   = (const float*)d_in[9];
  float* out = (float*)d_out;

  dim3 grid(BATCH / 64), block(64);
  sampler_kernel<<<grid, block, 0, stream>>>(mu, log_var, W_ih1, W_hh1, b_ih1,
                                             b_hh1, W_ih2, W_hh2, b_ih2, b_hh2, out);
}

// Round 5
// 22763.568 us; speedup vs baseline: 1.4195x; 1.4195x over previous
//
#include <hip/hip_runtime.h>
#include <stdint.h>
#include <math.h>

#define BATCH 32768
#define LDIM 128
#define HID 20
#define NG 80                       // 4*HID

// =====================================================================
// eps: jax.random.normal(key(42), (128,32768), f32), partitionable
// threefry scheme (counters (0, n), output o0^o1) — VERIFIED PASSING in
// round 4 (absmax 0.0156). Keep bit-exact: separately-rounded f32 ops,
// log1p via f64 (correctly-rounded f32 log1p).
// =====================================================================

__device__ __forceinline__ void threefry2x32(uint32_t x0, uint32_t x1,
                                             uint32_t& o0, uint32_t& o1) {
  const uint32_t k0 = 0u, k1 = 42u;
  const uint32_t k2 = k0 ^ k1 ^ 0x1BD11BDAu;
  uint32_t v0 = x0 + k0, v1 = x1 + k1;
#define TF_R(r) { v0 += v1; v1 = (v1 << (r)) | (v1 >> (32 - (r))); v1 ^= v0; }
  TF_R(13) TF_R(15) TF_R(26) TF_R(6)
  v0 += k1; v1 += k2 + 1u;
  TF_R(17) TF_R(29) TF_R(16) TF_R(24)
  v0 += k2; v1 += k0 + 2u;
  TF_R(13) TF_R(15) TF_R(26) TF_R(6)
  v0 += k0; v1 += k1 + 3u;
  TF_R(17) TF_R(29) TF_R(16) TF_R(24)
  v0 += k1; v1 += k2 + 4u;
  TF_R(13) TF_R(15) TF_R(26) TF_R(6)
  v0 += k2; v1 += k0 + 5u;
#undef TF_R
  o0 = v0; o1 = v1;
}

__device__ __forceinline__ float erfinv_xla_f32(float x) {
  float t = __fmul_rn(x, x);
  float w = -(float)log1p(-(double)t);   // correctly-rounded f32 log1p
  float p;
  if (w < 5.0f) {
    w = __fadd_rn(w, -2.5f);
    p = 2.81022636e-08f;
    p = __fadd_rn(__fmul_rn(p, w), 3.43273939e-07f);
    p = __fadd_rn(__fmul_rn(p, w), -3.5233877e-06f);
    p = __fadd_rn(__fmul_rn(p, w), -4.39150654e-06f);
    p = __fadd_rn(__fmul_rn(p, w), 0.00021858087f);
    p = __fadd_rn(__fmul_rn(p, w), -0.00125372503f);
    p = __fadd_rn(__fmul_rn(p, w), -0.00417768164f);
    p = __fadd_rn(__fmul_rn(p, w), 0.246640727f);
    p = __fadd_rn(__fmul_rn(p, w), 1.50140941f);
  } else {
    w = __fadd_rn(__fsqrt_rn(w), -3.0f);
    p = -0.000200214257f;
    p = __fadd_rn(__fmul_rn(p, w), 0.000100950558f);
    p = __fadd_rn(__fmul_rn(p, w), 0.00134934322f);
    p = __fadd_rn(__fmul_rn(p, w), -0.00367342844f);
    p = __fadd_rn(__fmul_rn(p, w), 0.00573950773f);
    p = __fadd_rn(__fmul_rn(p, w), -0.0076224613f);
    p = __fadd_rn(__fmul_rn(p, w), 0.00943887047f);
    p = __fadd_rn(__fmul_rn(p, w), 1.00167406f);
    p = __fadd_rn(__fmul_rn(p, w), 2.83297682f);
  }
  return __fmul_rn(p, x);
}

__device__ __forceinline__ float eps_val(int t, int b) {
  uint32_t n = (uint32_t)t * 32768u + (uint32_t)b;
  uint32_t o0, o1;
  threefry2x32(0u, n, o0, o1);
  uint32_t bits = o0 ^ o1;
  const float lo    = __uint_as_float(0xBF7FFFFFu);   // nextafter(-1,0) f32
  const float sqrt2 = __uint_as_float(0x3FB504F3u);   // float32(sqrt(2))
  float f = __fadd_rn(__uint_as_float((bits >> 9) | 0x3F800000u), -1.0f);
  float u = __fadd_rn(__fmul_rn(f, 2.0f), lo);
  u = fmaxf(u, lo);
  return __fmul_rn(sqrt2, erfinv_xla_f32(u));
}

// ---------- fp32 fast activations (hw exp2/rcp; recurrence is contracting,
// ~1e-7/step noise -> ~1e-4 final, far under the ~0.26 bf16-8ulp threshold) ----
__device__ __forceinline__ float fexp2(float x) { return __builtin_amdgcn_exp2f(x); }
__device__ __forceinline__ float frcp(float x)  { return __builtin_amdgcn_rcpf(x); }
__device__ __forceinline__ float fexp(float x)  { return fexp2(1.442695040888963f * x); }
__device__ __forceinline__ float sigm(float x)  { return frcp(1.0f + fexp2(-1.442695040888963f * x)); }
__device__ __forceinline__ float tanhx(float x) { return 1.0f - 2.0f * frcp(1.0f + fexp2(2.885390081777926f * x)); }

__global__ __launch_bounds__(64, 1) void sampler_kernel(
    const float* __restrict__ mu, const float* __restrict__ log_var,
    const float* __restrict__ W_ih1, const float* __restrict__ W_hh1,
    const float* __restrict__ b_ih1, const float* __restrict__ b_hh1,
    const float* __restrict__ W_ih2, const float* __restrict__ W_hh2,
    const float* __restrict__ b_ih2, const float* __restrict__ b_hh2,
    float* __restrict__ out) {
  __shared__ float sWihT[127 * NG];   // [col j][gate g]  (transposed W_ih1)
  __shared__ float sWhh1[NG * HID];   // [gate g][k] row-major
  __shared__ float sWih2T[40 * 8];    // [k][j]           (transposed W_ih2)
  __shared__ float sWhh2[16];         // [j][0..1]
  __shared__ float sB1[NG];           // b_ih1 + b_hh1
  __shared__ float sB2[8];            // b_ih2 + b_hh2

  const int tid = threadIdx.x;
  for (int i = tid; i < 127 * NG; i += 64) {
    int g = i / 127, j = i - g * 127;
    sWihT[j * NG + g] = W_ih1[i];
  }
  for (int i = tid; i < NG * HID; i += 64) sWhh1[i] = W_hh1[i];
  for (int i = tid; i < 320; i += 64) {
    int j = i / 40, k = i - j * 40;
    sWih2T[k * 8 + j] = W_ih2[i];
  }
  if (tid < 16) sWhh2[tid] = W_hh2[tid];
  if (tid < 8)  sB2[tid] = b_ih2[tid] + b_hh2[tid];
  for (int i = tid; i < NG; i += 64) sB1[i] = b_ih1[i] + b_hh1[i];
  __syncthreads();

  const int b = blockIdx.x * 64 + tid;
  const float* mrow = mu + (size_t)b * LDIM;

  // first_input = eps[0]*exp(0.5*log_var[:,0]) + mu[:,0]
  float eps0 = eps_val(0, b);
  float m0 = mrow[0];
  float fi = fmaf(eps0, fexp(0.5f * log_var[(size_t)b * LDIM]), m0);

  // prefix accumulator of x @ W_ih1^T; step-1 input = first_input in col 0
  float acc[NG];
#pragma unroll
  for (int g = 0; g < NG; ++g) acc[g] = fi * sWihT[g];

  float h[HID], c[HID];
#pragma unroll
  for (int k = 0; k < HID; ++k) { h[k] = 0.0f; c[k] = 0.0f; }
  float h2a = 0.0f, h2b = 0.0f, c2a = 0.0f, c2b = 0.0f;

  float* out_mu = out;
  float* out_lv = out + (size_t)BATCH * LDIM;
  float* out_sp = out + 2 * (size_t)BATCH * LDIM;
  const size_t rowoff = (size_t)b * LDIM;
  out_mu[rowoff] = 0.0f;
  out_lv[rowoff] = 1.0f;
  out_sp[rowoff] = fi;

  for (int t = 1; t < LDIM; ++t) {
    // ---- maintain acc = (mu cols 0..t-1) @ W_ih1^T ----
    if (t >= 2) {
      if (t == 2) {
        float d0 = m0 - fi;   // col 0 switches first_input -> mu[:,0]
        const float4* c4 = (const float4*)&sWihT[0];
#pragma unroll
        for (int q = 0; q < 20; ++q) {
          float4 w4 = c4[q];
          acc[4*q]   = fmaf(d0, w4.x, acc[4*q]);
          acc[4*q+1] = fmaf(d0, w4.y, acc[4*q+1]);
          acc[4*q+2] = fmaf(d0, w4.z, acc[4*q+2]);
          acc[4*q+3] = fmaf(d0, w4.w, acc[4*q+3]);
        }
      }
      float xm = mrow[t - 1];
      const float4* col4 = (const float4*)&sWihT[(t - 1) * NG];
#pragma unroll
      for (int q = 0; q < 20; ++q) {
        float4 w4 = col4[q];
        acc[4*q]   = fmaf(xm, w4.x, acc[4*q]);
        acc[4*q+1] = fmaf(xm, w4.y, acc[4*q+1]);
        acc[4*q+2] = fmaf(xm, w4.z, acc[4*q+2]);
        acc[4*q+3] = fmaf(xm, w4.w, acc[4*q+3]);
      }
    }

    // ---- LSTM2 gate init: biases + h2 @ W_hh2^T ----
    float g2[8];
#pragma unroll
    for (int j = 0; j < 8; ++j)
      g2[j] = sB2[j] + h2a * sWhh2[2 * j] + h2b * sWhh2[2 * j + 1];

    // ---- LSTM1 gates + cell, fused LSTM2 gate accumulation ----
    float hn[HID];
#pragma unroll
    for (int k = 0; k < HID; ++k) {
      float si = acc[k]      + sB1[k];
      float sf = acc[20 + k] + sB1[20 + k];
      float sg = acc[40 + k] + sB1[40 + k];
      float so = acc[60 + k] + sB1[60 + k];
      const float4* wi = (const float4*)&sWhh1[(k)      * HID];
      const float4* wf = (const float4*)&sWhh1[(20 + k) * HID];
      const float4* wg = (const float4*)&sWhh1[(40 + k) * HID];
      const float4* wo = (const float4*)&sWhh1[(60 + k) * HID];
#pragma unroll
      for (int q = 0; q < 5; ++q) {
        float4 a = wi[q], bq = wf[q], cq = wg[q], dq = wo[q];
        float h0 = h[4*q], h1v = h[4*q+1], h2v = h[4*q+2], h3 = h[4*q+3];
        si = fmaf(h0, a.x, si);  si = fmaf(h1v, a.y, si);
        si = fmaf(h2v, a.z, si); si = fmaf(h3, a.w, si);
        sf = fmaf(h0, bq.x, sf); sf = fmaf(h1v, bq.y, sf);
        sf = fmaf(h2v, bq.z, sf); sf = fmaf(h3, bq.w, sf);
        sg = fmaf(h0, cq.x, sg); sg = fmaf(h1v, cq.y, sg);
        sg = fmaf(h2v, cq.z, sg); sg = fmaf(h3, cq.w, sg);
        so = fmaf(h0, dq.x, so); so = fmaf(h1v, dq.y, so);
        so = fmaf(h2v, dq.z, so); so = fmaf(h3, dq.w, so);
      }
      float ik = sigm(si), fk = sigm(sf), gk = tanhx(sg), ok = sigm(so);
      float cn = fmaf(fk, c[k], ik * gk);
      c[k] = cn;
      float hk = ok * tanhx(cn);
      hn[k] = hk;
      float lh = (hk >= 0.0f) ? hk : 0.01f * hk;   // leaky_relu(h1)
      float lc = (cn >= 0.0f) ? cn : 0.01f * cn;   // leaky_relu(c1)
      const float4* uu = (const float4*)&sWih2T[k * 8];
      const float4* vv = (const float4*)&sWih2T[(20 + k) * 8];
      float4 u0 = uu[0], u1 = uu[1], v0 = vv[0], v1 = vv[1];
      g2[0] = fmaf(lh, u0.x, g2[0]); g2[1] = fmaf(lh, u0.y, g2[1]);
      g2[2] = fmaf(lh, u0.z, g2[2]); g2[3] = fmaf(lh, u0.w, g2[3]);
      g2[4] = fmaf(lh, u1.x, g2[4]); g2[5] = fmaf(lh, u1.y, g2[5]);
      g2[6] = fmaf(lh, u1.z, g2[6]); g2[7] = fmaf(lh, u1.w, g2[7]);
      g2[0] = fmaf(lc, v0.x, g2[0]); g2[1] = fmaf(lc, v0.y, g2[1]);
      g2[2] = fmaf(lc, v0.z, g2[2]); g2[3] = fmaf(lc, v0.w, g2[3]);
      g2[4] = fmaf(lc, v1.x, g2[4]); g2[5] = fmaf(lc, v1.y, g2[5]);
      g2[6] = fmaf(lc, v1.z, g2[6]); g2[7] = fmaf(lc, v1.w, g2[7]);
    }
#pragma unroll
    for (int k = 0; k < HID; ++k) h[k] = hn[k];

    // ---- LSTM2 cell (H2 = 2): i=g2[0:2], f=g2[2:4], g=g2[4:6], o=g2[6:8] ----
    float i20 = sigm(g2[0]), i21 = sigm(g2[1]);
    float f20 = sigm(g2[2]), f21 = sigm(g2[3]);
    float t20 = tanhx(g2[4]), t21 = tanhx(g2[5]);
    float o20 = sigm(g2[6]), o21 = sigm(g2[7]);
    c2a = fmaf(f20, c2a, i20 * t20);
    c2b = fmaf(f21, c2b, i21 * t21);
    h2a = o20 * tanhx(c2a);
    h2b = o21 * tanhx(c2b);

    // ---- sample + store ----
    float eps_t = eps_val(t, b);
    float sp = fmaf(eps_t, fexp(0.5f * h2b), h2a);
    out_mu[rowoff + t] = h2a;
    out_lv[rowoff + t] = h2b;
    out_sp[rowoff + t] = sp;
  }
}

extern "C" void kernel_launch(void* const* d_in, const int* in_sizes, int n_in,
                              void* d_out, int out_size, void* d_ws, size_t ws_size,
                              hipStream_t stream) {
  (void)in_sizes; (void)n_in; (void)d_ws; (void)ws_size; (void)out_size;
  const float* mu      = (const float*)d_in[0];
  const float* log_var = (const float*)d_in[1];
  const float* W_ih1   = (const float*)d_in[2];
  const float* W_hh1   = (const float*)d_in[3];
  const float* b_ih1   = (const float*)d_in[4];
  const float* b_hh1   = (const float*)d_in[5];
  const float* W_ih2   = (const float*)d_in[6];
  const float* W_hh2   = (const float*)d_in[7];
  const float* b_ih2   = (const float*)d_in[8];
  const float* b_hh2   = (const float*)d_in[9];
  float* out = (float*)d_out;

  dim3 grid(BATCH / 64), block(64);
  sampler_kernel<<<grid, block, 0, stream>>>(mu, log_var, W_ih1, W_hh1, b_ih1,
                                             b_hh1, W_ih2, W_hh2, b_ih2, b_hh2, out);
}

// Round 6
// 1251.048 us; speedup vs baseline: 25.8291x; 18.1956x over previous
//
#include <hip/hip_runtime.h>
#include <stdint.h>
#include <math.h>

#define BATCH 32768
#define LDIM 128
#define HID 20
#define NG 80                       // 4*HID

// =====================================================================
// eps: jax.random.normal(key(42), (128,32768), f32), partitionable
// threefry (counters (0,n), output o0^o1) — VERIFIED PASSING (r4/r5,
// absmax 0.0156 = 1 bf16 ulp). Do not touch.
// =====================================================================

__device__ __forceinline__ void threefry2x32(uint32_t x0, uint32_t x1,
                                             uint32_t& o0, uint32_t& o1) {
  const uint32_t k0 = 0u, k1 = 42u;
  const uint32_t k2 = k0 ^ k1 ^ 0x1BD11BDAu;
  uint32_t v0 = x0 + k0, v1 = x1 + k1;
#define TF_R(r) { v0 += v1; v1 = (v1 << (r)) | (v1 >> (32 - (r))); v1 ^= v0; }
  TF_R(13) TF_R(15) TF_R(26) TF_R(6)
  v0 += k1; v1 += k2 + 1u;
  TF_R(17) TF_R(29) TF_R(16) TF_R(24)
  v0 += k2; v1 += k0 + 2u;
  TF_R(13) TF_R(15) TF_R(26) TF_R(6)
  v0 += k0; v1 += k1 + 3u;
  TF_R(17) TF_R(29) TF_R(16) TF_R(24)
  v0 += k1; v1 += k2 + 4u;
  TF_R(13) TF_R(15) TF_R(26) TF_R(6)
  v0 += k2; v1 += k0 + 5u;
#undef TF_R
  o0 = v0; o1 = v1;
}

__device__ __forceinline__ float erfinv_xla_f32(float x) {
  float t = __fmul_rn(x, x);
  float w = -(float)log1p(-(double)t);   // correctly-rounded f32 log1p
  float p;
  if (w < 5.0f) {
    w = __fadd_rn(w, -2.5f);
    p = 2.81022636e-08f;
    p = __fadd_rn(__fmul_rn(p, w), 3.43273939e-07f);
    p = __fadd_rn(__fmul_rn(p, w), -3.5233877e-06f);
    p = __fadd_rn(__fmul_rn(p, w), -4.39150654e-06f);
    p = __fadd_rn(__fmul_rn(p, w), 0.00021858087f);
    p = __fadd_rn(__fmul_rn(p, w), -0.00125372503f);
    p = __fadd_rn(__fmul_rn(p, w), -0.00417768164f);
    p = __fadd_rn(__fmul_rn(p, w), 0.246640727f);
    p = __fadd_rn(__fmul_rn(p, w), 1.50140941f);
  } else {
    w = __fadd_rn(__fsqrt_rn(w), -3.0f);
    p = -0.000200214257f;
    p = __fadd_rn(__fmul_rn(p, w), 0.000100950558f);
    p = __fadd_rn(__fmul_rn(p, w), 0.00134934322f);
    p = __fadd_rn(__fmul_rn(p, w), -0.00367342844f);
    p = __fadd_rn(__fmul_rn(p, w), 0.00573950773f);
    p = __fadd_rn(__fmul_rn(p, w), -0.0076224613f);
    p = __fadd_rn(__fmul_rn(p, w), 0.00943887047f);
    p = __fadd_rn(__fmul_rn(p, w), 1.00167406f);
    p = __fadd_rn(__fmul_rn(p, w), 2.83297682f);
  }
  return __fmul_rn(p, x);
}

__device__ __forceinline__ float eps_val(int t, int b) {
  uint32_t n = (uint32_t)t * 32768u + (uint32_t)b;
  uint32_t o0, o1;
  threefry2x32(0u, n, o0, o1);
  uint32_t bits = o0 ^ o1;
  const float lo    = __uint_as_float(0xBF7FFFFFu);
  const float sqrt2 = __uint_as_float(0x3FB504F3u);
  float f = __fadd_rn(__uint_as_float((bits >> 9) | 0x3F800000u), -1.0f);
  float u = __fadd_rn(__fmul_rn(f, 2.0f), lo);
  u = fmaxf(u, lo);
  return __fmul_rn(sqrt2, erfinv_xla_f32(u));
}

__device__ __forceinline__ float fexp2(float x) { return __builtin_amdgcn_exp2f(x); }
__device__ __forceinline__ float frcp(float x)  { return __builtin_amdgcn_rcpf(x); }
__device__ __forceinline__ float fexp(float x)  { return fexp2(1.442695040888963f * x); }
__device__ __forceinline__ float sigm(float x)  { return frcp(1.0f + fexp2(-1.442695040888963f * x)); }
__device__ __forceinline__ float tanhx(float x) { return 1.0f - 2.0f * frcp(1.0f + fexp2(2.885390081777926f * x)); }

// 2 lanes per element: lane = 2*elem_local + role; role owns k in [10*role, 10*role+10)
__global__ __launch_bounds__(256, 1) void sampler_kernel(
    const float* __restrict__ mu, const float* __restrict__ log_var,
    const float* __restrict__ W_ih1, const float* __restrict__ W_hh1,
    const float* __restrict__ b_ih1, const float* __restrict__ b_hh1,
    const float* __restrict__ W_ih2, const float* __restrict__ W_hh2,
    const float* __restrict__ b_ih2, const float* __restrict__ b_hh2,
    float* __restrict__ out) {
  // role-split layouts: per-instruction only 2 distinct LDS addresses (broadcast)
  __shared__ __align__(16) float sWih1T[127 * NG];  // [j][role*40 + type*10 + kl]
  __shared__ __align__(16) float sWhh1[NG * HID];   // [((role*4+type)*10+kl)][j]
  __shared__ __align__(16) float sWih2[320];        // [((role*10+kl)*2+hc)][j=0..7]
  __shared__ __align__(16) float sB1s[NG];          // [role*40 + type*10 + kl]
  __shared__ __align__(16) float sWhh2[16];         // [j][0..1]
  __shared__ __align__(16) float sB2[8];

  const int tid = threadIdx.x;
  for (int i = tid; i < 127 * NG; i += 256) {
    int j = i / NG, q = i - j * NG;          // q = role*40 + type*10 + kl
    int role = q / 40, rem = q - role * 40;
    int type = rem / 10, kl = rem - type * 10;
    int g = type * 20 + role * 10 + kl;
    sWih1T[i] = W_ih1[g * 127 + j];
  }
  for (int i = tid; i < NG * HID; i += 256) {
    int j = i % HID, r = i / HID;            // r = (role*4+type)*10+kl
    int kl = r % 10, rt = r / 10;
    int role = rt >> 2, type = rt & 3;
    int g = type * 20 + role * 10 + kl;
    sWhh1[i] = W_hh1[g * HID + j];
  }
  for (int i = tid; i < 320; i += 256) {
    int j = i & 7, r = i >> 3;               // r = (role*10+kl)*2+hc
    int hc = r & 1, rk = r >> 1;
    int role = rk / 10, kl = rk - role * 10;
    sWih2[i] = W_ih2[j * 40 + hc * 20 + role * 10 + kl];
  }
  if (tid < 80) {
    int kl = tid % 10, q = tid / 10;
    int role = q >> 2, type = q & 3;
    int g = type * 20 + role * 10 + kl;
    sB1s[tid] = b_ih1[g] + b_hh1[g];
  }
  if (tid < 16) sWhh2[tid] = W_hh2[tid];
  if (tid < 8)  sB2[tid] = b_ih2[tid] + b_hh2[tid];
  __syncthreads();

  const int role = tid & 1;
  const int elem = blockIdx.x * 128 + (tid >> 1);
  const int rbase = role * 40;
  const float* mrow = mu + (size_t)elem * LDIM;

  // first_input (computed identically on both lanes of the pair)
  float eps0 = eps_val(0, elem);
  float m0 = mrow[0];
  float fi = fmaf(eps0, fexp(0.5f * log_var[(size_t)elem * LDIM]), m0);

  // acc_flat[i], i = type*10+kl — this lane's 40 gate accumulators
  float acc[40];
  {
    const float4* c4 = (const float4*)&sWih1T[rbase];
#pragma unroll
    for (int q = 0; q < 10; ++q) {
      float4 w4 = c4[q];
      acc[4*q]   = fi * w4.x; acc[4*q+1] = fi * w4.y;
      acc[4*q+2] = fi * w4.z; acc[4*q+3] = fi * w4.w;
    }
  }

  float h[HID], c[10];
#pragma unroll
  for (int k = 0; k < HID; ++k) h[k] = 0.0f;
#pragma unroll
  for (int k = 0; k < 10; ++k) c[k] = 0.0f;
  float h2a = 0.0f, h2b = 0.0f, c2a = 0.0f, c2b = 0.0f;

  float* out_mu = out;
  float* out_lv = out + (size_t)BATCH * LDIM;
  float* out_sp = out + 2 * (size_t)BATCH * LDIM;
  const size_t rowoff = (size_t)elem * LDIM;
  if (role == 0) { out_mu[rowoff] = 0.0f; out_lv[rowoff] = 1.0f; }
  else           { out_sp[rowoff] = fi; }

  for (int t = 1; t < LDIM; ++t) {
    // ---- maintain acc = (input cols) @ W_ih1^T  (prefix trick) ----
    if (t >= 2) {
      if (t == 2) {
        float d0 = m0 - fi;   // col 0 switches first_input -> mu[:,0]
        const float4* c4 = (const float4*)&sWih1T[rbase];
#pragma unroll
        for (int q = 0; q < 10; ++q) {
          float4 w4 = c4[q];
          acc[4*q]   = fmaf(d0, w4.x, acc[4*q]);
          acc[4*q+1] = fmaf(d0, w4.y, acc[4*q+1]);
          acc[4*q+2] = fmaf(d0, w4.z, acc[4*q+2]);
          acc[4*q+3] = fmaf(d0, w4.w, acc[4*q+3]);
        }
      }
      float xm = mrow[t - 1];
      const float4* col4 = (const float4*)&sWih1T[(t - 1) * NG + rbase];
#pragma unroll
      for (int q = 0; q < 10; ++q) {
        float4 w4 = col4[q];
        acc[4*q]   = fmaf(xm, w4.x, acc[4*q]);
        acc[4*q+1] = fmaf(xm, w4.y, acc[4*q+1]);
        acc[4*q+2] = fmaf(xm, w4.z, acc[4*q+2]);
        acc[4*q+3] = fmaf(xm, w4.w, acc[4*q+3]);
      }
    }

    // ---- LSTM2 gate init (redundant on both lanes; h2a/h2b replicated) ----
    float g2i[8], g2p[8];
#pragma unroll
    for (int j = 0; j < 8; ++j) {
      g2i[j] = sB2[j] + h2a * sWhh2[2 * j] + h2b * sWhh2[2 * j + 1];
      g2p[j] = 0.0f;
    }

    // ---- LSTM1: this lane's 10 k's (40 gates), fused LSTM2 partials ----
    float hn[10];
#pragma unroll
    for (int kl = 0; kl < 10; ++kl) {
      float s0 = acc[kl]      + sB1s[rbase + kl];
      float s1 = acc[10 + kl] + sB1s[rbase + 10 + kl];
      float s2 = acc[20 + kl] + sB1s[rbase + 20 + kl];
      float s3 = acc[30 + kl] + sB1s[rbase + 30 + kl];
      const float4* wi = (const float4*)&sWhh1[((role * 4 + 0) * 10 + kl) * HID];
      const float4* wf = (const float4*)&sWhh1[((role * 4 + 1) * 10 + kl) * HID];
      const float4* wg = (const float4*)&sWhh1[((role * 4 + 2) * 10 + kl) * HID];
      const float4* wo = (const float4*)&sWhh1[((role * 4 + 3) * 10 + kl) * HID];
#pragma unroll
      for (int q = 0; q < 5; ++q) {
        float4 a = wi[q], bq = wf[q], cq = wg[q], dq = wo[q];
        float v0 = h[4*q], v1 = h[4*q+1], v2 = h[4*q+2], v3 = h[4*q+3];
        s0 = fmaf(v0, a.x, s0);  s0 = fmaf(v1, a.y, s0);
        s0 = fmaf(v2, a.z, s0);  s0 = fmaf(v3, a.w, s0);
        s1 = fmaf(v0, bq.x, s1); s1 = fmaf(v1, bq.y, s1);
        s1 = fmaf(v2, bq.z, s1); s1 = fmaf(v3, bq.w, s1);
        s2 = fmaf(v0, cq.x, s2); s2 = fmaf(v1, cq.y, s2);
        s2 = fmaf(v2, cq.z, s2); s2 = fmaf(v3, cq.w, s2);
        s3 = fmaf(v0, dq.x, s3); s3 = fmaf(v1, dq.y, s3);
        s3 = fmaf(v2, dq.z, s3); s3 = fmaf(v3, dq.w, s3);
      }
      float ik = sigm(s0), fk = sigm(s1), gk = tanhx(s2), ok = sigm(s3);
      float cn = fmaf(fk, c[kl], ik * gk);
      c[kl] = cn;
      float hk = ok * tanhx(cn);
      hn[kl] = hk;
      float lh = (hk >= 0.0f) ? hk : 0.01f * hk;
      float lc = (cn >= 0.0f) ? cn : 0.01f * cn;
      const float4* uu = (const float4*)&sWih2[((role * 10 + kl) * 2 + 0) * 8];
      const float4* vv = (const float4*)&sWih2[((role * 10 + kl) * 2 + 1) * 8];
      float4 u0 = uu[0], u1 = uu[1], v0 = vv[0], v1 = vv[1];
      g2p[0] = fmaf(lh, u0.x, g2p[0]); g2p[1] = fmaf(lh, u0.y, g2p[1]);
      g2p[2] = fmaf(lh, u0.z, g2p[2]); g2p[3] = fmaf(lh, u0.w, g2p[3]);
      g2p[4] = fmaf(lh, u1.x, g2p[4]); g2p[5] = fmaf(lh, u1.y, g2p[5]);
      g2p[6] = fmaf(lh, u1.z, g2p[6]); g2p[7] = fmaf(lh, u1.w, g2p[7]);
      g2p[0] = fmaf(lc, v0.x, g2p[0]); g2p[1] = fmaf(lc, v0.y, g2p[1]);
      g2p[2] = fmaf(lc, v0.z, g2p[2]); g2p[3] = fmaf(lc, v0.w, g2p[3]);
      g2p[4] = fmaf(lc, v1.x, g2p[4]); g2p[5] = fmaf(lc, v1.y, g2p[5]);
      g2p[6] = fmaf(lc, v1.z, g2p[6]); g2p[7] = fmaf(lc, v1.w, g2p[7]);
    }

    // ---- h all-gather between the pair (xor-1 shuffle) ----
#pragma unroll
    for (int kl = 0; kl < 10; ++kl) {
      float own = hn[kl];
      float other = __shfl_xor(own, 1, 64);
      h[kl]      = role ? other : own;
      h[kl + 10] = role ? own   : other;
    }

    // ---- LSTM2 gates: pair-reduce partials, then cell (replicated) ----
    float g2[8];
#pragma unroll
    for (int j = 0; j < 8; ++j)
      g2[j] = g2i[j] + g2p[j] + __shfl_xor(g2p[j], 1, 64);

    float i20 = sigm(g2[0]), i21 = sigm(g2[1]);
    float f20 = sigm(g2[2]), f21 = sigm(g2[3]);
    float t20 = tanhx(g2[4]), t21 = tanhx(g2[5]);
    float o20 = sigm(g2[6]), o21 = sigm(g2[7]);
    c2a = fmaf(f20, c2a, i20 * t20);
    c2b = fmaf(f21, c2b, i21 * t21);
    h2a = o20 * tanhx(c2a);
    h2b = o21 * tanhx(c2b);

    // ---- sample + stores (role-split) ----
    float eps_t = eps_val(t, elem);
    float sp = fmaf(eps_t, fexp(0.5f * h2b), h2a);
    if (role == 0) { out_mu[rowoff + t] = h2a; out_lv[rowoff + t] = h2b; }
    else           { out_sp[rowoff + t] = sp; }
  }
}

extern "C" void kernel_launch(void* const* d_in, const int* in_sizes, int n_in,
                              void* d_out, int out_size, void* d_ws, size_t ws_size,
                              hipStream_t stream) {
  (void)in_sizes; (void)n_in; (void)d_ws; (void)ws_size; (void)out_size;
  const float* mu      = (const float*)d_in[0];
  const float* log_var = (const float*)d_in[1];
  const float* W_ih1   = (const float*)d_in[2];
  const float* W_hh1   = (const float*)d_in[3];
  const float* b_ih1   = (const float*)d_in[4];
  const float* b_hh1   = (const float*)d_in[5];
  const float* W_ih2   = (const float*)d_in[6];
  const float* W_hh2   = (const float*)d_in[7];
  const float* b_ih2   = (const float*)d_in[8];
  const float* b_hh2   = (const float*)d_in[9];
  float* out = (float*)d_out;

  dim3 grid(BATCH / 128), block(256);   // 2 lanes per element
  sampler_kernel<<<grid, block, 0, stream>>>(mu, log_var, W_ih1, W_hh1, b_ih1,
                                             b_hh1, W_ih2, W_hh2, b_ih2, b_hh2, out);
}